// Round 8
// baseline (62.595 us; speedup 1.0000x reference)
//
#include <hip/hip_runtime.h>

// ---------------------------------------------------------------------------
// EfficentLePE, block-local: block = (window w, head-pair g).
// Window = [128 rows x 8 cols] tokens; head h <-> channels [h*16,(h+1)*16).
//   A[h] = softmax_e( SCALE * sum_n K[n,d] V[n,e] )   (16x16)
//   out[n,e] = sum_d Q[n,d] A[h][d,e] + depthwise3x3(Q)[n,e] + bias
// R4 structure. Single change vs R4: pass-2 Q-tile rows padded to 260 floats
// (1040 B). Row stride 256 ≡ 0 mod 32 banks made every ldcol / q-read an
// 8-way bank conflict (lanes differ in row); 260 % 32 = 4 shifts each row by
// 4 banks -> residual aliasing is 2-way (free). No per-access address math.
// ---------------------------------------------------------------------------

static constexpr int BB   = 8;
static constexpr int RES  = 128;
static constexpr int DIM  = 128;
static constexpr int WSP  = 8;
static constexpr int L    = RES * RES;   // 16384
static constexpr float SCALE = 0.25f;    // HD^-0.5, HD=16
static constexpr int QROW = 260;         // padded floats per Q buffer row
static constexpr int QBUF = 18 * QROW;   // 4680 floats per Q buffer

#define GLD_LDS16(g, l)                                                        \
  __builtin_amdgcn_global_load_lds(                                            \
      (const __attribute__((address_space(1))) void*)(const void*)(g),         \
      (__attribute__((address_space(3))) void*)(l), 16, 0, 0)

__global__ __launch_bounds__(256, 2) void fused_lepe(
    const float* __restrict__ Qg, const float* __restrict__ Kg,
    const float* __restrict__ Vg, const float* __restrict__ cw,
    const float* __restrict__ cb, float* __restrict__ outp) {
  // smem map (floats):
  //  pass1: K dbuf [0,8192) (2 x 4096), V dbuf [8192,16384)
  //  scratch [0,2048)                  (after pass1; K buf dead)
  //  pass2: Qbuf0 [0,4680), Qbuf1 [4680,9360)
  //  A_sm  [16384,16896)
  __shared__ float smem[16896];
  float* const A_sm    = smem + 16384;
  float* const scratch = smem;

  const int b  = blockIdx.x;            // 0..511
  const int w  = b >> 2, g = b & 3;     // window, head-group (2 heads)
  const int bi = w >> 4, wb = w & 15;   // batch, window-col
  const int t  = threadIdx.x;
  const int wave = t >> 6, lane = t & 63;
  const size_t win_base = (size_t)(bi * L + wb * WSP) * DIM;
  const int ch0 = g * 32;               // first global channel of this group

  // ======== Pass 1: Gram = K^T V, 8 tiles of 16 image rows (R4 exact) =====
  // accum mapping per wave: h1 = lane>>5, dq=(lane>>3)&3, ep=lane&7
  const int h1 = lane >> 5, dq = (lane >> 3) & 3, ep = lane & 7;
  const int kaddr = h1 * 16 + dq * 4;
  const int vaddr = h1 * 16 + ep * 2;
  const int n0 = wave * 32;             // this wave's token quarter of tile

  float a00=0.f,a01=0.f,a10=0.f,a11=0.f,a20=0.f,a21=0.f,a30=0.f,a31=0.f;

  auto stageKV = [&](int tile, int buf) {
    // 32 chunks: mat (K/V) x 16 rows; 8 per wave. Chunk = 8 tokens x 32 ch.
    for (int c = wave; c < 32; c += 4) {
      const int mat = c >> 4, rr = c & 15;
      const int r = tile * 16 + rr;     // image row
      const float* src = (mat ? Vg : Kg) + win_base +
                         (size_t)r * (RES * DIM) + (lane >> 3) * DIM + ch0 +
                         (lane & 7) * 4;
      float* dst = smem + mat * 8192 + buf * 4096 + rr * 256;
      GLD_LDS16(src, dst);
    }
  };

  stageKV(0, 0);
  __syncthreads();
  for (int tt = 0; tt < 8; ++tt) {
    const int cur = tt & 1;
    if (tt < 7) stageKV(tt + 1, cur ^ 1);
    const float* Kb = smem + cur * 4096;
    const float* Vb = smem + 8192 + cur * 4096;
#pragma unroll 4
    for (int n = n0; n < n0 + 32; ++n) {
      const float4 k4 = *reinterpret_cast<const float4*>(&Kb[n * 32 + kaddr]);
      const float2 v2 = *reinterpret_cast<const float2*>(&Vb[n * 32 + vaddr]);
      a00 += k4.x * v2.x; a01 += k4.x * v2.y;
      a10 += k4.y * v2.x; a11 += k4.y * v2.y;
      a20 += k4.z * v2.x; a21 += k4.z * v2.y;
      a30 += k4.w * v2.x; a31 += k4.w * v2.y;
    }
    __syncthreads();
  }

  // ======== Q-tile staging (18 rows incl. halos, PADDED rows) =============
  auto stageQ = [&](int tile, int buf) {
    const int r0 = tile * 16;
    float* qb = smem + buf * QBUF;
    for (int c = wave; c < 18; c += 4) {
      const int r = r0 - 1 + c;         // image row for buffer row c
      float* dst = qb + c * QROW;       // 1040B slot; 1KB chunk written
      if ((unsigned)r < 128u) {
        const float* src = Qg + win_base + (size_t)r * (RES * DIM) +
                           (lane >> 3) * DIM + ch0 + (lane & 7) * 4;
        GLD_LDS16(src, dst);
      } else {
        *reinterpret_cast<float4*>(dst + lane * 4) =
            make_float4(0.f, 0.f, 0.f, 0.f);
      }
    }
  };

  // issue Q tile 0 into buf1 (latency hides under reduce), write partials
  stageQ(0, 1);
  {
    float* sc = scratch + wave * 512 + lane * 8;
    sc[0]=a00; sc[1]=a01; sc[2]=a10; sc[3]=a11;
    sc[4]=a20; sc[5]=a21; sc[6]=a30; sc[7]=a31;
  }
  __syncthreads();                       // scratch visible

  // ======== reduce 4 wave-copies + softmax over e -> A_sm[h*16+d][e] ======
  {
    const int r = t >> 3, e2 = t & 7;    // r = h*16+d, e in {2e2, 2e2+1}
    const int h = r >> 4, d = r & 15;
    const int f = (h * 32 + (d >> 2) * 8 + e2) * 8 + (d & 3) * 2;
    float v0 = (scratch[f]     + scratch[512 + f]     + scratch[1024 + f]     + scratch[1536 + f]) * SCALE;
    float v1 = (scratch[f + 1] + scratch[512 + f + 1] + scratch[1024 + f + 1] + scratch[1536 + f + 1]) * SCALE;
    float m = fmaxf(v0, v1);
    m = fmaxf(m, __shfl_xor(m, 1));
    m = fmaxf(m, __shfl_xor(m, 2));
    m = fmaxf(m, __shfl_xor(m, 4));
    v0 = __expf(v0 - m); v1 = __expf(v1 - m);
    float ss = v0 + v1;
    ss += __shfl_xor(ss, 1);
    ss += __shfl_xor(ss, 2);
    ss += __shfl_xor(ss, 4);
    const float ri = 1.0f / ss;
    A_sm[r * 16 + e2 * 2 + 0] = v0 * ri;
    A_sm[r * 16 + e2 * 2 + 1] = v1 * ri;
  }
  __syncthreads();                       // A_sm ready; Q tile 0 drained

  // ======== Pass 2 setup: per-thread A column, conv weights, bias =========
  const int cq   = t & 7;                // channel quad (4 ch) within 32
  const int lr   = (t >> 3) & 15;        // local output row in tile
  const int half = t >> 7;               // wl range: half*4 .. half*4+3
  const int hg = cq >> 2, e0 = (cq & 3) * 4;
  const int cg = ch0 + cq * 4;           // global channel quad base

  float4 Acol[16];
#pragma unroll
  for (int d = 0; d < 16; ++d)
    Acol[d] = *reinterpret_cast<const float4*>(&A_sm[(hg * 16 + d) * 16 + e0]);
  float4 wgt[9];
#pragma unroll
  for (int tap = 0; tap < 9; ++tap) {
    wgt[tap].x = cw[(cg + 0) * 9 + tap];
    wgt[tap].y = cw[(cg + 1) * 9 + tap];
    wgt[tap].z = cw[(cg + 2) * 9 + tap];
    wgt[tap].w = cw[(cg + 3) * 9 + tap];
  }
  const float4 bias = *reinterpret_cast<const float4*>(&cb[cg]);
  const float4 zero4 = make_float4(0.f, 0.f, 0.f, 0.f);

#define ACC(qs, d)                                                             \
  o.x += (qs) * Acol[d].x; o.y += (qs) * Acol[d].y;                            \
  o.z += (qs) * Acol[d].z; o.w += (qs) * Acol[d].w;

  // ======== Pass 2 main loop: 8 tiles of 16 rows, double-buffered =========
  int buf = 1;
  for (int tile = 0; tile < 8; ++tile) {
    if (tile < 7) stageQ(tile + 1, buf ^ 1);
    const float* Qb = smem + buf * QBUF;
    const int r0 = tile * 16;
    const int w0 = half * 4;

    float4 cL[3], cC[3], cR[3];
    auto ldcol = [&](int cidx, float4* dv) {
#pragma unroll
      for (int dy = 0; dy < 3; ++dy)
        dv[dy] = ((unsigned)cidx < 8u)
                     ? *reinterpret_cast<const float4*>(
                           &Qb[(lr + dy) * QROW + cidx * 32 + cq * 4])
                     : zero4;
    };
    ldcol(w0 - 1, cL);
    ldcol(w0, cC);

#pragma unroll
    for (int k = 0; k < 4; ++k) {
      const int wl = w0 + k;
      ldcol(wl + 1, cR);
      float4 o = bias;
#pragma unroll
      for (int dy = 0; dy < 3; ++dy) {
        const int t0 = dy * 3;
        o.x += cL[dy].x * wgt[t0].x + cC[dy].x * wgt[t0+1].x + cR[dy].x * wgt[t0+2].x;
        o.y += cL[dy].y * wgt[t0].y + cC[dy].y * wgt[t0+1].y + cR[dy].y * wgt[t0+2].y;
        o.z += cL[dy].z * wgt[t0].z + cC[dy].z * wgt[t0+1].z + cR[dy].z * wgt[t0+2].z;
        o.w += cL[dy].w * wgt[t0].w + cC[dy].w * wgt[t0+1].w + cR[dy].w * wgt[t0+2].w;
      }
      // attention: Q[token, hg*16..+15] . Acol  (token buffer row = lr+1)
      const float* qr = &Qb[(lr + 1) * QROW + wl * 32 + hg * 16];
      const float4 q0 = *reinterpret_cast<const float4*>(qr + 0);
      const float4 q1 = *reinterpret_cast<const float4*>(qr + 4);
      const float4 q2 = *reinterpret_cast<const float4*>(qr + 8);
      const float4 q3 = *reinterpret_cast<const float4*>(qr + 12);
      ACC(q0.x, 0)  ACC(q0.y, 1)  ACC(q0.z, 2)  ACC(q0.w, 3)
      ACC(q1.x, 4)  ACC(q1.y, 5)  ACC(q1.z, 6)  ACC(q1.w, 7)
      ACC(q2.x, 8)  ACC(q2.y, 9)  ACC(q2.z, 10) ACC(q2.w, 11)
      ACC(q3.x, 12) ACC(q3.y, 13) ACC(q3.z, 14) ACC(q3.w, 15)

      float* dst = outp + win_base + (size_t)(r0 + lr) * (RES * DIM) +
                   wl * DIM + cg;
      *reinterpret_cast<float4*>(dst) = o;

#pragma unroll
      for (int dy = 0; dy < 3; ++dy) { cL[dy] = cC[dy]; cC[dy] = cR[dy]; }
    }
    __syncthreads();
    buf ^= 1;
  }
#undef ACC
}

// ---------------------------------------------------------------------------
extern "C" void kernel_launch(void* const* d_in, const int* in_sizes, int n_in,
                              void* d_out, int out_size, void* d_ws,
                              size_t ws_size, hipStream_t stream) {
  const float* qkv = (const float*)d_in[0];
  const float* cw  = (const float*)d_in[1];
  const float* cb  = (const float*)d_in[2];
  const float* Qg = qkv;
  const float* Kg = qkv + (size_t)BB * L * DIM;
  const float* Vg = Kg + (size_t)BB * L * DIM;
  float* outp = (float*)d_out;

  fused_lepe<<<512, 256, 0, stream>>>(Qg, Kg, Vg, cw, cb, outp);
}